// Round 1
// baseline (135.816 us; speedup 1.0000x reference)
//
#include <hip/hip_runtime.h>
#include <hip/hip_bf16.h>

typedef float f32x4 __attribute__((ext_vector_type(4)));
typedef short bf16x8 __attribute__((ext_vector_type(8)));
typedef unsigned short us4 __attribute__((ext_vector_type(4)));

#define NB 16
#define NC 256
#define NTOK 4096
#define NHID 128
#define NM 384
#define NT 128
#define NTILES 32

// LDS row pads (in ushorts). Row strides are 16B * odd -> b128-aligned, low bank conflict.
#define APAD 264   // 528 B rows for x_t tile [tok][c]
#define BPAD 40    // 80 B rows for W tile [m][32]
#define PPAD 136   // 272 B rows for post buffer [m][tok]
#define JPAD 136   // 272 B rows for K3 tiles

#define K1_SMEM 104448  // max(A 67584 + B 30720, post 104448)
#define K3_SMEM 104448  // Qs 34816 + Ms 69632

__device__ __forceinline__ unsigned short f2bf(float f) {
  union { float f; unsigned u; } v; v.f = f;
  return (unsigned short)((v.u + 0x7fffu + ((v.u >> 16) & 1u)) >> 16);
}
__device__ __forceinline__ float bf2f(unsigned short h) {
  union { unsigned u; float f; } v; v.u = ((unsigned)h) << 16;
  return v.f;
}

// ---------------------------------------------------------------------------
// K1: per (b, token-tile of 128):
//   D[tok][m] = sum_c x[b][c][tok] * W[m][c]   (m: 0-127 q, 128-255 k, 256-383 v)
//   q: softmax over 32-wide head dim (cols) * 32^-0.5  -> qt[b][n][j] bf16
//   k: exp(k) (no max-sub; safe fp32 range)            -> LDS
//   v: passthrough                                     -> LDS
//   partial context  P[b][tile][h][e][d] = sum_tok ek[d,tok] v[e,tok]
//   partial denom    S[b][tile][d]       = sum_tok ek[d,tok]
// ---------------------------------------------------------------------------
__global__ __launch_bounds__(512, 2) void k1_qkv(
    const float* __restrict__ x, const float* __restrict__ Wq,
    const float* __restrict__ Wk, const float* __restrict__ Wv,
    unsigned short* __restrict__ qt, float* __restrict__ Pp, float* __restrict__ Sp)
{
  __shared__ __align__(16) unsigned char smem[K1_SMEM];
  unsigned short* As = (unsigned short*)smem;            // [128][APAD] bf16 (GEMM phase)
  unsigned short* Bs = (unsigned short*)(smem + 67584);  // [384][BPAD] bf16 (GEMM phase)
  unsigned short* post = (unsigned short*)smem;          // [384][PPAD] bf16 (post phase)

  const int tile = blockIdx.x, b = blockIdx.y;
  const int n0 = tile * NT;
  const int t = threadIdx.x;
  const int wid = t >> 6, l = t & 63;
  const int l16 = l & 15, lhi = l >> 4;

  // ---- stage A: transpose x[b][c][n0:n0+128] fp32 -> As[tok][c] bf16 (pack 2 c's per b32 write)
  {
    const int tq = t & 15;
    const int cr = t >> 4;
    const float* xb = x + ((size_t)b * NC) * NTOK + n0;
#pragma unroll
    for (int i = 0; i < 4; ++i) {
      const int c0 = 2 * cr + 64 * i;
      const float* r0 = xb + (size_t)c0 * NTOK;
      const float* r1 = r0 + NTOK;
      const float4 a0 = *(const float4*)(r0 + 4 * tq);
      const float4 b0v = *(const float4*)(r1 + 4 * tq);
      const float4 a1 = *(const float4*)(r0 + 64 + 4 * tq);
      const float4 b1v = *(const float4*)(r1 + 64 + 4 * tq);
      const float* pa0 = (const float*)&a0; const float* pb0 = (const float*)&b0v;
      const float* pa1 = (const float*)&a1; const float* pb1 = (const float*)&b1v;
#pragma unroll
      for (int j = 0; j < 4; ++j) {
        *(unsigned*)&As[(4 * tq + j) * APAD + c0] =
            (unsigned)f2bf(pa0[j]) | ((unsigned)f2bf(pb0[j]) << 16);
        *(unsigned*)&As[(64 + 4 * tq + j) * APAD + c0] =
            (unsigned)f2bf(pa1[j]) | ((unsigned)f2bf(pb1[j]) << 16);
      }
    }
  }

  // ---- GEMM: 8 waves as 2(tok) x 4(m); wave tile 64 tok x 96 m
  f32x4 acc[4][6];
#pragma unroll
  for (int i = 0; i < 4; ++i)
#pragma unroll
    for (int j = 0; j < 6; ++j) acc[i][j] = 0;

  const int tokb = (wid >> 2) * 64;
  const int mb = (wid & 3) * 96;

  for (int ks = 0; ks < 8; ++ks) {
    __syncthreads();  // Bs safe to overwrite (and, iter 0, As writes done)
#pragma unroll
    for (int i = 0; i < 6; ++i) {
      const int s = t + 512 * i;
      const int m = s >> 3, ch = s & 7;
      const float* wsrc = (m < 128) ? (Wq + (size_t)m * NC)
                        : (m < 256) ? (Wk + (size_t)(m - 128) * NC)
                                    : (Wv + (size_t)(m - 256) * NC);
      const float4 wv = *(const float4*)(wsrc + ks * 32 + ch * 4);
      us4 p;
      p[0] = f2bf(wv.x); p[1] = f2bf(wv.y); p[2] = f2bf(wv.z); p[3] = f2bf(wv.w);
      *(us4*)&Bs[m * BPAD + ch * 4] = p;
    }
    __syncthreads();
    bf16x8 af[4];
#pragma unroll
    for (int tf = 0; tf < 4; ++tf)
      af[tf] = *(const bf16x8*)&As[(tokb + tf * 16 + l16) * APAD + ks * 32 + lhi * 8];
#pragma unroll
    for (int nf = 0; nf < 6; ++nf) {
      const bf16x8 bfv = *(const bf16x8*)&Bs[(mb + nf * 16 + l16) * BPAD + lhi * 8];
#pragma unroll
      for (int tf = 0; tf < 4; ++tf)
        acc[tf][nf] = __builtin_amdgcn_mfma_f32_16x16x32_bf16(af[tf], bfv, acc[tf][nf], 0, 0, 0);
    }
  }
  __syncthreads();  // GEMM LDS dead; reuse as `post`

  // ---- epilogue transforms -> post[m][tok] bf16
  const float qscale = 0.1767766952966369f;  // 32^-0.5
#pragma unroll
  for (int p = 0; p < 3; ++p) {
    const int mg = mb + p * 32;  // wave-uniform
#pragma unroll
    for (int tf = 0; tf < 4; ++tf) {
      f32x4 v0 = acc[tf][2 * p], v1 = acc[tf][2 * p + 1];
      if (mg < 128) {  // q: softmax over the 32 cols (2 frags x 16 lanes)
#pragma unroll
        for (int r = 0; r < 4; ++r) {
          float mx = fmaxf(v0[r], v1[r]);
          mx = fmaxf(mx, __shfl_xor(mx, 1));
          mx = fmaxf(mx, __shfl_xor(mx, 2));
          mx = fmaxf(mx, __shfl_xor(mx, 4));
          mx = fmaxf(mx, __shfl_xor(mx, 8));
          const float e0 = __expf(v0[r] - mx), e1 = __expf(v1[r] - mx);
          float s = e0 + e1;
          s += __shfl_xor(s, 1); s += __shfl_xor(s, 2);
          s += __shfl_xor(s, 4); s += __shfl_xor(s, 8);
          const float inv = qscale / s;
          v0[r] = e0 * inv; v1[r] = e1 * inv;
        }
      } else if (mg < 256) {  // k: exp (no max-sub; |k|<~5 for N(0,1) data)
#pragma unroll
        for (int r = 0; r < 4; ++r) { v0[r] = __expf(v0[r]); v1[r] = __expf(v1[r]); }
      }
      const int tok = tokb + tf * 16 + lhi * 4;
      us4 p0, p1;
#pragma unroll
      for (int r = 0; r < 4; ++r) { p0[r] = f2bf(v0[r]); p1[r] = f2bf(v1[r]); }
      *(us4*)&post[(mg + l16) * PPAD + tok] = p0;
      *(us4*)&post[(mg + 16 + l16) * PPAD + tok] = p1;
    }
  }
  __syncthreads();

  // ---- context partials (waves 0-3, head = wid) / S partials (waves 4-7)
  if (wid < 4) {
    const int h = wid;
    f32x4 ca[2][2];
    ca[0][0] = 0; ca[0][1] = 0; ca[1][0] = 0; ca[1][1] = 0;
#pragma unroll
    for (int ks = 0; ks < 4; ++ks) {
      bf16x8 ae[2], be[2];
#pragma unroll
      for (int d = 0; d < 2; ++d)
        ae[d] = *(const bf16x8*)&post[(128 + h * 32 + d * 16 + l16) * PPAD + ks * 32 + lhi * 8];
#pragma unroll
      for (int e = 0; e < 2; ++e)
        be[e] = *(const bf16x8*)&post[(256 + h * 32 + e * 16 + l16) * PPAD + ks * 32 + lhi * 8];
#pragma unroll
      for (int d = 0; d < 2; ++d)
#pragma unroll
        for (int e = 0; e < 2; ++e)
          ca[d][e] = __builtin_amdgcn_mfma_f32_16x16x32_bf16(ae[d], be[e], ca[d][e], 0, 0, 0);
    }
    // C[d][e]: col=e=l16(+16e), row=d=lhi*4+r(+16d). Store transposed P[..][e][d] -> float4 in d.
    float* pb = Pp + (((size_t)(b * NTILES + tile) * 4 + h) << 10);
#pragma unroll
    for (int d = 0; d < 2; ++d)
#pragma unroll
      for (int e = 0; e < 2; ++e) {
        const int ei = e * 16 + l16, d0 = d * 16 + lhi * 4;
        *(f32x4*)&pb[ei * 32 + d0] = ca[d][e];
      }
  } else {
    const int d = (wid - 4) * 32 + (l >> 1);
    const int half = l & 1;
    const unsigned short* rowp = &post[(128 + d) * PPAD + half * 64];
    float s = 0.f;
#pragma unroll
    for (int k2 = 0; k2 < 16; ++k2) {
      const us4 v = *(const us4*)&rowp[k2 * 4];
      s += bf2f(v[0]) + bf2f(v[1]) + bf2f(v[2]) + bf2f(v[3]);
    }
    s += __shfl_xor(s, 1);
    if (half == 0) Sp[((size_t)b * NTILES + tile) * 128 + d] = s;
  }

  // ---- q write-out: post[0..127][tok] -> qt[b][n0+tok][j] (token-major bf16)
  {
    const int tok = t >> 2, jc = t & 3;
    unsigned short* dst = qt + ((size_t)(b * NTOK + n0 + tok)) * NHID + jc * 32;
#pragma unroll
    for (int k = 0; k < 4; ++k) {
      uint4 u;
      unsigned* pu = (unsigned*)&u;
#pragma unroll
      for (int jj = 0; jj < 4; ++jj) {
        const unsigned short lo = post[(jc * 32 + k * 8 + 2 * jj) * PPAD + tok];
        const unsigned short hi = post[(jc * 32 + k * 8 + 2 * jj + 1) * PPAD + tok];
        pu[jj] = (unsigned)lo | ((unsigned)hi << 16);
      }
      *(uint4*)(dst + 8 * k) = u;
    }
  }
}

// ---------------------------------------------------------------------------
// K2a: reduce partials over 32 tiles; Cn[b][h][e][d] = P / (S[h*32+d] * 4096)
// ---------------------------------------------------------------------------
__global__ __launch_bounds__(256) void k2_reduce(
    const float* __restrict__ Pp, const float* __restrict__ Sp, float* __restrict__ Cn)
{
  __shared__ float Ss[128];
  const int b = blockIdx.x, t = threadIdx.x;
  if (t < 128) {
    float s = 0.f;
    for (int tile = 0; tile < NTILES; ++tile)
      s += Sp[((size_t)b * NTILES + tile) * 128 + t];
    Ss[t] = s * 4096.0f;
  }
  __syncthreads();
  float accv[16];
#pragma unroll
  for (int i = 0; i < 16; ++i) accv[i] = 0.f;
  const float* pb = Pp + (size_t)b * NTILES * 4096;
  for (int tile = 0; tile < NTILES; ++tile) {
#pragma unroll
    for (int i = 0; i < 16; ++i)
      accv[i] += pb[tile * 4096 + t + 256 * i];
  }
#pragma unroll
  for (int i = 0; i < 16; ++i) {
    const int idx = t + 256 * i;
    const int h = idx >> 10, d = idx & 31;
    Cn[(size_t)b * 4096 + idx] = accv[i] / Ss[h * 32 + d];
  }
}

// ---------------------------------------------------------------------------
// K2b: M[b][c][h*32+d] = sum_e Wo[c][h*32+e] * Cn[b][h][e][d]  (bf16 out)
// ---------------------------------------------------------------------------
__global__ __launch_bounds__(256) void k2_m(
    const float* __restrict__ Wo, const float* __restrict__ Cn, unsigned short* __restrict__ Mm)
{
  const int co = blockIdx.x, b = blockIdx.y;
  const int t = threadIdx.x;
  const int c = co * 32 + (t >> 3), jq = t & 7;
  const float* wrow = Wo + (size_t)c * NHID;
  const float* cb = Cn + (size_t)b * 4096;
#pragma unroll
  for (int jj = 0; jj < 16; ++jj) {
    const int j = jq * 16 + jj;
    const int h = j >> 5, d = j & 31;
    const float* ch_ = cb + h * 1024 + d;
    const float* wr = wrow + h * 32;
    float s = 0.f;
#pragma unroll
    for (int e = 0; e < 32; ++e) s += wr[e] * ch_[e * 32];
    Mm[((size_t)b * NC + c) * NHID + j] = f2bf(s);
  }
}

// ---------------------------------------------------------------------------
// K3: out[b][c][n] = LN_c( sum_j M[b][c][j]*qt[b][n][j] + bo[c] ) * g[c]
// ---------------------------------------------------------------------------
__global__ __launch_bounds__(512, 2) void k3_out(
    const unsigned short* __restrict__ qt, const unsigned short* __restrict__ Mm,
    const float* __restrict__ bo, const float* __restrict__ g, float* __restrict__ out)
{
  __shared__ __align__(16) unsigned char smem[K3_SMEM];
  unsigned short* Qs = (unsigned short*)smem;            // [128][JPAD]
  unsigned short* Ms = (unsigned short*)(smem + 34816);  // [256][JPAD]
  float* red = (float*)smem;                             // [4][128][2] after GEMM

  const int tile = blockIdx.x, b = blockIdx.y;
  const int n0 = tile * NT;
  const int t = threadIdx.x;
  const int wid = t >> 6, l = t & 63;
  const int l16 = l & 15, lhi = l >> 4;

  {
    const int tok = t >> 2, c4 = t & 3;
    const unsigned short* src = qt + ((size_t)(b * NTOK + n0 + tok)) * NHID + c4 * 32;
#pragma unroll
    for (int k = 0; k < 4; ++k)
      *(uint4*)&Qs[tok * JPAD + c4 * 32 + 8 * k] = *(const uint4*)(src + 8 * k);
  }
  {
    const int c = t >> 1, half = t & 1;
    const unsigned short* src = Mm + ((size_t)b * NC + c) * NHID + half * 64;
#pragma unroll
    for (int k = 0; k < 8; ++k)
      *(uint4*)&Ms[c * JPAD + half * 64 + 8 * k] = *(const uint4*)(src + 8 * k);
  }
  __syncthreads();

  f32x4 acc[4][4];
#pragma unroll
  for (int i = 0; i < 4; ++i)
#pragma unroll
    for (int j = 0; j < 4; ++j) acc[i][j] = 0;

  const int tokb = (wid >> 2) * 64;
  const int cb_ = (wid & 3) * 64;
#pragma unroll
  for (int ks = 0; ks < 4; ++ks) {
    bf16x8 af[4], bfv[4];
#pragma unroll
    for (int tf = 0; tf < 4; ++tf)
      af[tf] = *(const bf16x8*)&Qs[(tokb + tf * 16 + l16) * JPAD + ks * 32 + lhi * 8];
#pragma unroll
    for (int cf = 0; cf < 4; ++cf)
      bfv[cf] = *(const bf16x8*)&Ms[(cb_ + cf * 16 + l16) * JPAD + ks * 32 + lhi * 8];
#pragma unroll
    for (int tf = 0; tf < 4; ++tf)
#pragma unroll
      for (int cf = 0; cf < 4; ++cf)
        acc[tf][cf] = __builtin_amdgcn_mfma_f32_16x16x32_bf16(af[tf], bfv[cf], acc[tf][cf], 0, 0, 0);
  }
  __syncthreads();  // LDS reusable as reduction scratch

  float bol[4], gl[4];
#pragma unroll
  for (int cf = 0; cf < 4; ++cf) {
    const int c = cb_ + cf * 16 + l16;
    bol[cf] = bo[c]; gl[cf] = g[c];
  }
#pragma unroll
  for (int tf = 0; tf < 4; ++tf)
#pragma unroll
    for (int cf = 0; cf < 4; ++cf)
#pragma unroll
      for (int r = 0; r < 4; ++r) acc[tf][cf][r] += bol[cf];

#pragma unroll
  for (int tf = 0; tf < 4; ++tf)
#pragma unroll
    for (int r = 0; r < 4; ++r) {
      float s = 0.f, q2 = 0.f;
#pragma unroll
      for (int cf = 0; cf < 4; ++cf) {
        const float v = acc[tf][cf][r];
        s += v; q2 += v * v;
      }
      s += __shfl_xor(s, 1); q2 += __shfl_xor(q2, 1);
      s += __shfl_xor(s, 2); q2 += __shfl_xor(q2, 2);
      s += __shfl_xor(s, 4); q2 += __shfl_xor(q2, 4);
      s += __shfl_xor(s, 8); q2 += __shfl_xor(q2, 8);
      if (l16 == 0) {
        const int tok = tokb + tf * 16 + lhi * 4 + r;
        red[((wid & 3) * 128 + tok) * 2] = s;
        red[((wid & 3) * 128 + tok) * 2 + 1] = q2;
      }
    }
  __syncthreads();

  float mean[4][4], rstd[4][4];
#pragma unroll
  for (int tf = 0; tf < 4; ++tf)
#pragma unroll
    for (int r = 0; r < 4; ++r) {
      const int tok = tokb + tf * 16 + lhi * 4 + r;
      float s = 0.f, q2 = 0.f;
#pragma unroll
      for (int cg = 0; cg < 4; ++cg) {
        s += red[(cg * 128 + tok) * 2];
        q2 += red[(cg * 128 + tok) * 2 + 1];
      }
      const float mu = s * (1.0f / 256.0f);
      const float var = q2 * (1.0f / 256.0f) - mu * mu;  // biased, matches jnp.var
      mean[tf][r] = mu;
      rstd[tf][r] = rsqrtf(var + 1e-5f);
    }

  float* ob = out + ((size_t)b * NC) * NTOK + n0;
#pragma unroll
  for (int tf = 0; tf < 4; ++tf)
#pragma unroll
    for (int cf = 0; cf < 4; ++cf) {
      const int c = cb_ + cf * 16 + l16;
      f32x4 ov;
#pragma unroll
      for (int r = 0; r < 4; ++r)
        ov[r] = (acc[tf][cf][r] - mean[tf][r]) * rstd[tf][r] * gl[cf];
      *(f32x4*)&ob[(size_t)c * NTOK + tokb + tf * 16 + lhi * 4] = ov;
    }
}

// ---------------------------------------------------------------------------
extern "C" void kernel_launch(void* const* d_in, const int* in_sizes, int n_in,
                              void* d_out, int out_size, void* d_ws, size_t ws_size,
                              hipStream_t stream) {
  const float* x  = (const float*)d_in[0];
  const float* Wq = (const float*)d_in[1];
  const float* Wk = (const float*)d_in[2];
  const float* Wv = (const float*)d_in[3];
  const float* Wo = (const float*)d_in[4];
  const float* bo = (const float*)d_in[5];
  const float* g  = (const float*)d_in[6];
  float* out = (float*)d_out;

  char* ws = (char*)d_ws;
  unsigned short* qt = (unsigned short*)(ws);             // 16 MiB  [16][4096][128] bf16
  float* Pp = (float*)(ws + 16777216);                    // 8 MiB   [16][32][4][32][32] f32
  float* Sp = (float*)(ws + 25165824);                    // 256 KiB [16][32][128] f32
  float* Cn = (float*)(ws + 25427968);                    // 256 KiB [16][4][32][32] f32
  unsigned short* Mm = (unsigned short*)(ws + 25690112);  // 1 MiB   [16][256][128] bf16
  (void)ws_size; (void)in_sizes; (void)n_in; (void)out_size;

  hipLaunchKernelGGL(k1_qkv, dim3(NTILES, NB), dim3(512), 0, stream, x, Wq, Wk, Wv, qt, Pp, Sp);
  hipLaunchKernelGGL(k2_reduce, dim3(NB), dim3(256), 0, stream, Pp, Sp, Cn);
  hipLaunchKernelGGL(k2_m, dim3(8, NB), dim3(256), 0, stream, Wo, Cn, Mm);
  hipLaunchKernelGGL(k3_out, dim3(NTILES, NB), dim3(512), 0, stream, qt, Mm, bo, g, out);
}

// Round 2
// 92.162 us; speedup vs baseline: 1.4737x; 1.4737x over previous
//
#include <hip/hip_runtime.h>
#include <hip/hip_bf16.h>

typedef float f32x4 __attribute__((ext_vector_type(4)));
typedef short bf16x8 __attribute__((ext_vector_type(8)));
typedef unsigned short us4 __attribute__((ext_vector_type(4)));
typedef unsigned short us8 __attribute__((ext_vector_type(8)));

#define NB 16
#define NC 256
#define NTOK 4096
#define NHID 128

#define APAD 264   // As row stride (ushorts): 528 B, b128-aligned
#define PK 68      // postKV row stride: 136 B
#define PQ 132     // postQ row stride: 264 B

__device__ __forceinline__ unsigned short f2bf(float f) {
  union { float f; unsigned u; } v; v.f = f;
  return (unsigned short)((v.u + 0x7fffu + ((v.u >> 16) & 1u)) >> 16);
}
__device__ __forceinline__ float bf2f(unsigned short h) {
  union { unsigned u; float f; } v; v.u = ((unsigned)h) << 16;
  return v.f;
}

// ---------------------------------------------------------------------------
// k0: W (Wq|Wk|Wv rows, fp32) -> bf16 in MFMA B-frag per-lane order.
// Frag (mt, ks): lane l holds W[mt*16 + (l&15)][ks*32 + (l>>4)*8 .. +8].
// ---------------------------------------------------------------------------
__global__ __launch_bounds__(512) void k0_w(
    const float* __restrict__ Wq, const float* __restrict__ Wk,
    const float* __restrict__ Wv, unsigned short* __restrict__ Wswz)
{
  const int mt = blockIdx.x;            // 0..23
  const int t = threadIdx.x;
  const int ks = t >> 6, l = t & 63;
  const int m = mt * 16 + (l & 15);
  const int col = ks * 32 + (l >> 4) * 8;
  const float* src = (m < 128) ? (Wq + (size_t)m * NC)
                   : (m < 256) ? (Wk + (size_t)(m - 128) * NC)
                               : (Wv + (size_t)(m - 256) * NC);
  const float4 w0 = *(const float4*)(src + col);
  const float4 w1 = *(const float4*)(src + col + 4);
  us8 p;
  p[0] = f2bf(w0.x); p[1] = f2bf(w0.y); p[2] = f2bf(w0.z); p[3] = f2bf(w0.w);
  p[4] = f2bf(w1.x); p[5] = f2bf(w1.y); p[6] = f2bf(w1.z); p[7] = f2bf(w1.w);
  *(us8*)&Wswz[((size_t)(mt * 8 + ks)) * 512 + l * 8] = p;
}

// ---------------------------------------------------------------------------
// k1: per (b, 64-token tile): QKV GEMM (W-frags straight from global, no
// barriers in K-loop), q head-softmax, k exp + S col-sums from acc (fp32),
// context partials via MFMA, q written out in A-frag swizzled order.
// LDS: As[64][264] (33792 B) aliased under postKV[256][68] (34816 B);
// postQ[64][132] (16896 B) after -> 51712 B total.
// ---------------------------------------------------------------------------
__global__ __launch_bounds__(512, 4) void k1_qkv(
    const float* __restrict__ x, const unsigned short* __restrict__ Wswz,
    unsigned short* __restrict__ qswz, unsigned short* __restrict__ Pp,
    float* __restrict__ Sp)
{
  __shared__ __align__(16) unsigned char smem[51712];
  unsigned short* As = (unsigned short*)smem;              // [64][APAD]
  unsigned short* postKV = (unsigned short*)smem;          // [256][PK] (ek 0-127, v 128-255)
  unsigned short* postQ = (unsigned short*)(smem + 34816); // [64][PQ]

  const int tile = blockIdx.x, b = blockIdx.y;
  const int n0 = tile * 64;
  const int t = threadIdx.x;
  const int wid = t >> 6, l = t & 63;
  const int l16 = l & 15, lhi = l >> 4;
  const int tokh = wid >> 2;     // token half 0..1 (32 toks each)
  const int mw = wid & 3;        // m-group 0..3 (96 m each)
  const int mb = mw * 96;

  // ---- stage x^T tile: As[tok][c] bf16 (pack 2 c per b32)
  {
    const int slot = t & 15;     // tok/4
    const int cp0 = t >> 4;      // c-pair 0..31
    const float* xb = x + ((size_t)b * NC) * NTOK + n0;
#pragma unroll
    for (int i = 0; i < 4; ++i) {
      const int c0 = 2 * (cp0 + 32 * i);
      const float4 a0 = *(const float4*)(xb + (size_t)c0 * NTOK + slot * 4);
      const float4 a1 = *(const float4*)(xb + (size_t)(c0 + 1) * NTOK + slot * 4);
      const float* p0 = (const float*)&a0;
      const float* p1 = (const float*)&a1;
#pragma unroll
      for (int j = 0; j < 4; ++j)
        *(unsigned*)&As[(slot * 4 + j) * APAD + c0] =
            (unsigned)f2bf(p0[j]) | ((unsigned)f2bf(p1[j]) << 16);
    }
  }
  __syncthreads();

  // ---- GEMM: wave tile 32 tok x 96 m, K=256. No barriers inside.
  f32x4 acc[2][6];
#pragma unroll
  for (int i = 0; i < 2; ++i)
#pragma unroll
    for (int j = 0; j < 6; ++j) acc[i][j] = 0;

  const int mt0 = mw * 6;
  for (int ks = 0; ks < 8; ++ks) {
    bf16x8 af[2];
#pragma unroll
    for (int tf = 0; tf < 2; ++tf)
      af[tf] = *(const bf16x8*)&As[(tokh * 32 + tf * 16 + l16) * APAD + ks * 32 + lhi * 8];
#pragma unroll
    for (int nf = 0; nf < 6; ++nf) {
      const bf16x8 bfv = *(const bf16x8*)&Wswz[((size_t)((mt0 + nf) * 8 + ks)) * 512 + l * 8];
#pragma unroll
      for (int tf = 0; tf < 2; ++tf)
        acc[tf][nf] = __builtin_amdgcn_mfma_f32_16x16x32_bf16(af[tf], bfv, acc[tf][nf], 0, 0, 0);
    }
  }

  // ---- epilogue transforms (registers only)
  const float qscale = 0.1767766952966369f;  // 32^-0.5
#pragma unroll
  for (int pr = 0; pr < 3; ++pr) {
    const int mg = mb + pr * 32;
    if (mg < 128) {  // q: softmax over 32-wide head dim (frag pair, l16 lanes)
#pragma unroll
      for (int tf = 0; tf < 2; ++tf)
#pragma unroll
        for (int r = 0; r < 4; ++r) {
          const float a0 = acc[tf][2 * pr][r], a1 = acc[tf][2 * pr + 1][r];
          float mx = fmaxf(a0, a1);
          mx = fmaxf(mx, __shfl_xor(mx, 1));
          mx = fmaxf(mx, __shfl_xor(mx, 2));
          mx = fmaxf(mx, __shfl_xor(mx, 4));
          mx = fmaxf(mx, __shfl_xor(mx, 8));
          const float e0 = __expf(a0 - mx), e1 = __expf(a1 - mx);
          float s = e0 + e1;
          s += __shfl_xor(s, 1); s += __shfl_xor(s, 2);
          s += __shfl_xor(s, 4); s += __shfl_xor(s, 8);
          const float inv = qscale / s;
          acc[tf][2 * pr][r] = e0 * inv;
          acc[tf][2 * pr + 1][r] = e1 * inv;
        }
    } else if (mg < 256) {  // k: exp (no max-sub needed) + S col sums (fp32)
#pragma unroll
      for (int f = 0; f < 2; ++f) {
        float s = 0.f;
#pragma unroll
        for (int tf = 0; tf < 2; ++tf)
#pragma unroll
          for (int r = 0; r < 4; ++r) {
            const float e = __expf(acc[tf][2 * pr + f][r]);
            acc[tf][2 * pr + f][r] = e;
            s += e;
          }
        s += __shfl_xor(s, 16);
        s += __shfl_xor(s, 32);
        if (l < 16)
          Sp[(((size_t)b * 64 + tile) * 2 + tokh) * 128 + (mg - 128) + f * 16 + l16] = s;
      }
    }
  }
  __syncthreads();  // all GEMM As reads done -> safe to overwrite with postKV

  // ---- write postKV (ek, v as [row][tok]) and postQ (q as [tok][j])
#pragma unroll
  for (int nf = 0; nf < 6; ++nf) {
    const int mg = mb + nf * 16;
    if (mg < 128) {
#pragma unroll
      for (int tf = 0; tf < 2; ++tf) {
        const int tok = tokh * 32 + tf * 16 + lhi * 4;
#pragma unroll
        for (int r = 0; r < 4; ++r)
          postQ[(tok + r) * PQ + mg + l16] = f2bf(acc[tf][nf][r]);
      }
    } else {
      const int row = mg - 128 + l16;  // ek rows 0-127, v rows 128-255
#pragma unroll
      for (int tf = 0; tf < 2; ++tf) {
        us4 p;
#pragma unroll
        for (int r = 0; r < 4; ++r) p[r] = f2bf(acc[tf][nf][r]);
        *(us4*)&postKV[row * PK + tokh * 32 + tf * 16 + lhi * 4] = p;
      }
    }
  }
  __syncthreads();

  // ---- waves 4-7: context partials; waves 0-3: q swizzled write-out
  if (wid >= 4) {
    const int h = wid - 4;
    f32x4 ca[2][2];
    ca[0][0] = 0; ca[0][1] = 0; ca[1][0] = 0; ca[1][1] = 0;
#pragma unroll
    for (int ks2 = 0; ks2 < 2; ++ks2) {
      bf16x8 ae[2], be[2];
#pragma unroll
      for (int d = 0; d < 2; ++d)
        ae[d] = *(const bf16x8*)&postKV[(h * 32 + d * 16 + l16) * PK + ks2 * 32 + lhi * 8];
#pragma unroll
      for (int e = 0; e < 2; ++e)
        be[e] = *(const bf16x8*)&postKV[(128 + h * 32 + e * 16 + l16) * PK + ks2 * 32 + lhi * 8];
#pragma unroll
      for (int d = 0; d < 2; ++d)
#pragma unroll
        for (int e = 0; e < 2; ++e)
          ca[d][e] = __builtin_amdgcn_mfma_f32_16x16x32_bf16(ae[d], be[e], ca[d][e], 0, 0, 0);
    }
    // D[d][e]: col=e (l16), row=d (lhi*4+r). Store Pp[h][e][d] bf16.
    unsigned short* pb = Pp + (((size_t)b * 64 + tile) * 4 + h) * 1024;
#pragma unroll
    for (int d = 0; d < 2; ++d)
#pragma unroll
      for (int e = 0; e < 2; ++e) {
        us4 p;
#pragma unroll
        for (int r = 0; r < 4; ++r) p[r] = f2bf(ca[d][e][r]);
        *(us4*)&pb[(e * 16 + l16) * 32 + d * 16 + lhi * 4] = p;
      }
  } else {
    const int g = wid;  // 16-tok group 0..3
#pragma unroll
    for (int ks = 0; ks < 4; ++ks) {
      const bf16x8 v = *(const bf16x8*)&postQ[(g * 16 + l16) * PQ + ks * 32 + lhi * 8];
      *(bf16x8*)&qswz[(((size_t)(b * 256 + tile * 4 + g)) * 4 + ks) * 512 + l * 8] = v;
    }
  }
}

// ---------------------------------------------------------------------------
// k2a: per (h,b): Stot[d] = sum_{128 halves} Sp; Cn[h][e][d] = sum_tiles Pp / (Stot*4096)
// ---------------------------------------------------------------------------
__global__ __launch_bounds__(256) void k2_reduce(
    const unsigned short* __restrict__ Pp, const float* __restrict__ Sp,
    float* __restrict__ Cn)
{
  __shared__ float Ss[32];
  const int h = blockIdx.x, b = blockIdx.y;
  const int t = threadIdx.x;
  if (t < 32) {
    float s = 0.f;
    const float* sb = Sp + (size_t)b * 16384 + h * 32 + t;
    for (int i = 0; i < 128; ++i) s += sb[i * 128];
    Ss[t] = 1.0f / (s * 4096.0f);
  }
  __syncthreads();
  const int e = t >> 3, d4 = (t & 7) * 4;
  f32x4 a = 0;
  for (int tile = 0; tile < 64; ++tile) {
    const us4 v = *(const us4*)&Pp[(((size_t)b * 64 + tile) * 4 + h) * 1024 + e * 32 + d4];
    a[0] += bf2f(v[0]); a[1] += bf2f(v[1]); a[2] += bf2f(v[2]); a[3] += bf2f(v[3]);
  }
  f32x4 o;
#pragma unroll
  for (int j = 0; j < 4; ++j) o[j] = a[j] * Ss[d4 + j];
  *(f32x4*)&Cn[(size_t)b * 4096 + h * 1024 + e * 32 + d4] = o;
}

// ---------------------------------------------------------------------------
// k2b: M[b][c][j=(h,d)] = sum_e Wo[c][h*32+e] * Cn[h][e][d] -> bf16, MFMA
// B-frag swizzled order (frag = (ct, ks), lane l: c=ct*16+(l&15), j=ks*32+(l>>4)*8..).
// ---------------------------------------------------------------------------
__global__ __launch_bounds__(256) void k2_m(
    const float* __restrict__ Wo, const float* __restrict__ Cn,
    unsigned short* __restrict__ Mswz)
{
  const int ct = blockIdx.x, b = blockIdx.y;  // ct 0..15
  const int t = threadIdx.x;
  const int ks = t >> 6, l = t & 63;          // ks = h
  const int c = ct * 16 + (l & 15);
  const int d0 = (l >> 4) * 8;
  const float* wr = Wo + (size_t)c * NHID + ks * 32;
  const float* cb = Cn + (size_t)b * 4096 + ks * 1024;
  f32x4 s0 = 0, s1 = 0;
#pragma unroll 8
  for (int e = 0; e < 32; ++e) {
    const float w = wr[e];
    const f32x4 c0 = *(const f32x4*)&cb[e * 32 + d0];
    const f32x4 c1 = *(const f32x4*)&cb[e * 32 + d0 + 4];
#pragma unroll
    for (int j = 0; j < 4; ++j) { s0[j] += w * c0[j]; s1[j] += w * c1[j]; }
  }
  us8 p;
#pragma unroll
  for (int j = 0; j < 4; ++j) { p[j] = f2bf(s0[j]); p[4 + j] = f2bf(s1[j]); }
  *(us8*)&Mswz[(((size_t)b * 16 + ct) * 4 + ks) * 512 + l * 8] = p;
}

// ---------------------------------------------------------------------------
// k3: out[b][c][n] = LN_c( sum_j M[c][j] q[n][j] + bo[c] ) * g[c]
// Zero GEMM LDS: A-frags from qswz, B-frags from Mswz (both pre-swizzled).
// Block: 256 thr = 4 waves (c-groups of 64), 64-token tile.
// ---------------------------------------------------------------------------
__global__ __launch_bounds__(256, 3) void k3_out(
    const unsigned short* __restrict__ qswz, const unsigned short* __restrict__ Mswz,
    const float* __restrict__ bo, const float* __restrict__ g, float* __restrict__ out)
{
  __shared__ float red[4 * 64 * 2];
  const int bx = blockIdx.x, b = blockIdx.y;
  const int t = threadIdx.x;
  const int wid = t >> 6, l = t & 63;
  const int l16 = l & 15, lhi = l >> 4;

  bf16x8 mf[4][4];
#pragma unroll
  for (int cf = 0; cf < 4; ++cf)
#pragma unroll
    for (int ks = 0; ks < 4; ++ks)
      mf[cf][ks] = *(const bf16x8*)&Mswz[(((size_t)b * 16 + wid * 4 + cf) * 4 + ks) * 512 + l * 8];

  f32x4 acc[4][4];
#pragma unroll
  for (int i = 0; i < 4; ++i)
#pragma unroll
    for (int j = 0; j < 4; ++j) acc[i][j] = 0;

#pragma unroll
  for (int tf = 0; tf < 4; ++tf) {
    bf16x8 qf[4];
#pragma unroll
    for (int ks = 0; ks < 4; ++ks)
      qf[ks] = *(const bf16x8*)&qswz[(((size_t)(b * 256 + bx * 4 + tf)) * 4 + ks) * 512 + l * 8];
#pragma unroll
    for (int ks = 0; ks < 4; ++ks)
#pragma unroll
      for (int cf = 0; cf < 4; ++cf)
        acc[tf][cf] = __builtin_amdgcn_mfma_f32_16x16x32_bf16(qf[ks], mf[cf][ks], acc[tf][cf], 0, 0, 0);
  }

  float bol[4], gl[4];
#pragma unroll
  for (int cf = 0; cf < 4; ++cf) {
    const int c = wid * 64 + cf * 16 + l16;
    bol[cf] = bo[c]; gl[cf] = g[c];
  }
#pragma unroll
  for (int tf = 0; tf < 4; ++tf)
#pragma unroll
    for (int cf = 0; cf < 4; ++cf)
#pragma unroll
      for (int r = 0; r < 4; ++r) acc[tf][cf][r] += bol[cf];

#pragma unroll
  for (int tf = 0; tf < 4; ++tf)
#pragma unroll
    for (int r = 0; r < 4; ++r) {
      float s = 0.f, q2 = 0.f;
#pragma unroll
      for (int cf = 0; cf < 4; ++cf) {
        const float v = acc[tf][cf][r];
        s += v; q2 += v * v;
      }
      s += __shfl_xor(s, 1); q2 += __shfl_xor(q2, 1);
      s += __shfl_xor(s, 2); q2 += __shfl_xor(q2, 2);
      s += __shfl_xor(s, 4); q2 += __shfl_xor(q2, 4);
      s += __shfl_xor(s, 8); q2 += __shfl_xor(q2, 8);
      if (l16 == 0) {
        const int tok = tf * 16 + lhi * 4 + r;
        red[(wid * 64 + tok) * 2] = s;
        red[(wid * 64 + tok) * 2 + 1] = q2;
      }
    }
  __syncthreads();

  float mean[4][4], rstd[4][4];
#pragma unroll
  for (int tf = 0; tf < 4; ++tf)
#pragma unroll
    for (int r = 0; r < 4; ++r) {
      const int tok = tf * 16 + lhi * 4 + r;
      float s = 0.f, q2 = 0.f;
#pragma unroll
      for (int cg = 0; cg < 4; ++cg) {
        s += red[(cg * 64 + tok) * 2];
        q2 += red[(cg * 64 + tok) * 2 + 1];
      }
      const float mu = s * (1.0f / 256.0f);
      const float var = q2 * (1.0f / 256.0f) - mu * mu;
      mean[tf][r] = mu;
      rstd[tf][r] = rsqrtf(var + 1e-5f);
    }

  float* ob = out + ((size_t)b * NC) * NTOK + bx * 64;
#pragma unroll
  for (int tf = 0; tf < 4; ++tf)
#pragma unroll
    for (int cf = 0; cf < 4; ++cf) {
      const int c = wid * 64 + cf * 16 + l16;
      f32x4 ov;
#pragma unroll
      for (int r = 0; r < 4; ++r)
        ov[r] = (acc[tf][cf][r] - mean[tf][r]) * rstd[tf][r] * gl[cf];
      *(f32x4*)&ob[(size_t)c * NTOK + tf * 16 + lhi * 4] = ov;
    }
}

// ---------------------------------------------------------------------------
extern "C" void kernel_launch(void* const* d_in, const int* in_sizes, int n_in,
                              void* d_out, int out_size, void* d_ws, size_t ws_size,
                              hipStream_t stream) {
  const float* x  = (const float*)d_in[0];
  const float* Wq = (const float*)d_in[1];
  const float* Wk = (const float*)d_in[2];
  const float* Wv = (const float*)d_in[3];
  const float* Wo = (const float*)d_in[4];
  const float* bo = (const float*)d_in[5];
  const float* g  = (const float*)d_in[6];
  float* out = (float*)d_out;

  char* ws = (char*)d_ws;
  unsigned short* Wswz = (unsigned short*)(ws);            // 192 KiB
  unsigned short* qswz = (unsigned short*)(ws + 262144);   // 16 MiB  [16][256][4][512] bf16
  unsigned short* Pp   = (unsigned short*)(ws + 17039360); // 8 MiB   [16][64][4][32][32] bf16
  float*          Sp   = (float*)(ws + 25427968);          // 1 MiB   [16][64][2][128] f32
  float*          Cn   = (float*)(ws + 26476544);          // 256 KiB [16][4][32][32] f32
  unsigned short* Mswz = (unsigned short*)(ws + 26738688); // 1 MiB   [16][16][4][512] bf16
  (void)ws_size; (void)in_sizes; (void)n_in; (void)out_size;

  hipLaunchKernelGGL(k0_w, dim3(24), dim3(512), 0, stream, Wq, Wk, Wv, Wswz);
  hipLaunchKernelGGL(k1_qkv, dim3(64, NB), dim3(512), 0, stream, x, Wswz, qswz, Pp, Sp);
  hipLaunchKernelGGL(k2_reduce, dim3(4, NB), dim3(256), 0, stream, Pp, Sp, Cn);
  hipLaunchKernelGGL(k2_m, dim3(16, NB), dim3(256), 0, stream, Wo, Cn, Mswz);
  hipLaunchKernelGGL(k3_out, dim3(64, NB), dim3(256), 0, stream, qswz, Mswz, bo, g, out);
}